// Round 17
// baseline (172.130 us; speedup 1.0000x reference)
//
#include <hip/hip_runtime.h>
#include <hip/hip_bf16.h>

#define NROWS 131072
#define DK    1024
#define CCLS  21
#define CTF   84
#define NCOL  105          // 21 + 84
#define NCT   7            // 112 padded cols / 16
#define BM    32           // rows per block = two MFMA row-tiles (B amortized)
#define SLABF 256          // f32 per row per slab = 1KB contiguous per load
#define NSLAB (DK / SLABF) // 4

typedef __attribute__((ext_vector_type(4))) float f32x4;
typedef __attribute__((ext_vector_type(8))) short bf16x8;
typedef __attribute__((ext_vector_type(2))) unsigned int u32x2;

__device__ __forceinline__ unsigned short f2bf_rne(float x) {
    union { float f; unsigned u; } v; v.f = x;
    unsigned r = v.u + 0x7fffu + ((v.u >> 16) & 1u);
    return (unsigned short)(r >> 16);
}

__device__ __forceinline__ unsigned pack2(float lo, float hi) {
    union { float f; unsigned u; } a, b; a.f = lo; b.f = hi;
    return ((a.u + 0x8000u) >> 16) | ((b.u + 0x8000u) & 0xffff0000u);
}

// Pack [W_cls | W_tf | zero-pad] into bf16 MFMA B-fragment order (verified):
// element ((kt*NCT+ct)*64+lane)*8 + j = B[k][col],
// col = ct*16 + (lane&15), k = kt*32 + (lane>>4)*8 + j
__global__ void pack_B_kernel(const float* __restrict__ Wc,
                              const float* __restrict__ Wt,
                              unsigned short* __restrict__ Bp) {
    const int frag = blockIdx.x;           // 224 total
    const int kt = frag / NCT, ct = frag % NCT;
    const int lane = threadIdx.x;          // 64
    const int col = ct * 16 + (lane & 15);
    const int k0  = kt * 32 + ((lane >> 4) << 3);
    bf16x8 o;
#pragma unroll
    for (int j = 0; j < 8; ++j) {
        const int k = k0 + j;
        float v = 0.0f;
        if (col < CCLS)      v = Wc[k * CCLS + col];
        else if (col < NCOL) v = Wt[k * CTF + (col - CCLS)];
        o[j] = (short)f2bf_rne(v);
    }
    *reinterpret_cast<bf16x8*>(Bp + ((size_t)frag * 64 + lane) * 8) = o;
}

// R13 schedule at BM=32: per-block B traffic (229 KB) now serves 32 rows,
// halving the dominant L2->L1 vector-path stream. Per slab, issue order is
// [B x14][A(s+1) x8]; compute's B-waits retire only B (vmcnt FIFO), the A
// prefetch flies through compute+write. Each wave: 2 row-tiles x 7 col-tiles,
// K-split across 4 waves; two-pass LDS reduce epilogue.
__global__ __launch_bounds__(256, 3)
void roi_gemm_kernel(const float* __restrict__ F,
                     const unsigned short* __restrict__ Bp,
                     const float* __restrict__ bcls,
                     const float* __restrict__ btf,
                     float* __restrict__ out) {
    // staging: 2 bufs x 32 rows x 512B bf16 = 32 KB; reduce overlay = 28 KB
    __shared__ __align__(16) unsigned char smem[32768];

    const int t    = threadIdx.x;
    const int wave = t >> 6;
    const int lane = t & 63;
    const int fr   = lane & 15;      // A row-in-tile / B col
    const int fq   = lane >> 4;      // 0..3
    const long rw  = (long)blockIdx.x * BM;

    const unsigned short* bb = Bp + (size_t)lane * 8;
    // wave stages rows wave*8..wave*8+7; lane covers 16B at col lane*4
    const float* abase = F + (size_t)(rw + wave * 8) * DK + lane * 4;

    f32x4 acc[2][NCT];
#pragma unroll
    for (int rt = 0; rt < 2; ++rt)
#pragma unroll
        for (int ct = 0; ct < NCT; ++ct)
            acc[rt][ct] = (f32x4){0.f, 0.f, 0.f, 0.f};

    // LDS addresses (bf16 tile, 512B/row, 16B-chunk XOR swizzle by row&7):
#define AWADDR(BUF, Q) (smem + (BUF) * 16384 + (wave * 8 + (Q)) * 512 +       \
    (((lane >> 1) ^ ((wave * 8 + (Q)) & 7)) << 4) + ((lane & 1) << 3))

    // ---- prologue: load + write slab 0
    {
        f32x4 v0[8];
#pragma unroll
        for (int q = 0; q < 8; ++q)
            v0[q] = *reinterpret_cast<const f32x4*>(abase + (size_t)q * DK);
#pragma unroll
        for (int q = 0; q < 8; ++q) {
            u32x2 d;
            d[0] = pack2(v0[q][0], v0[q][1]);
            d[1] = pack2(v0[q][2], v0[q][3]);
            *reinterpret_cast<u32x2*>(AWADDR(0, q)) = d;
        }
    }
    __syncthreads();

#pragma unroll
    for (int s = 0; s < NSLAB; ++s) {
        const int buf = s & 1;

        // [1] ALL B-fragment loads for slab s — FIRST in the VMEM FIFO
        bf16x8 bfr[2][NCT];
#pragma unroll
        for (int jj = 0; jj < 2; ++jj) {
            const int ktg = s * 8 + wave * 2 + jj;
#pragma unroll
            for (int ct = 0; ct < NCT; ++ct)
                bfr[jj][ct] = *reinterpret_cast<const bf16x8*>(
                    bb + ((size_t)(ktg * NCT + ct) * 512));
        }
        __builtin_amdgcn_sched_barrier(0);

        // [2] A prefetch for slab s+1 — AFTER B, so B-waits keep it in flight
        f32x4 v[8];
        if (s + 1 < NSLAB) {
#pragma unroll
            for (int q = 0; q < 8; ++q)
                v[q] = *reinterpret_cast<const f32x4*>(
                    abase + (size_t)q * DK + (s + 1) * SLABF);
        }
        __builtin_amdgcn_sched_barrier(0);

        // [3] compute slab s: 2 k-tiles x 2 row-tiles x 7 col-tiles
#pragma unroll
        for (int jj = 0; jj < 2; ++jj) {
            const int lt = wave * 2 + jj;
            bf16x8 a[2];
#pragma unroll
            for (int rt = 0; rt < 2; ++rt)
                a[rt] = *reinterpret_cast<const bf16x8*>(
                    smem + buf * 16384 + (rt * 16 + fr) * 512 +
                    ((((lt << 2) | fq) ^ (fr & 7)) << 4));
#pragma unroll
            for (int ct = 0; ct < NCT; ++ct) {
                acc[0][ct] = __builtin_amdgcn_mfma_f32_16x16x32_bf16(
                    a[0], bfr[jj][ct], acc[0][ct], 0, 0, 0);
                acc[1][ct] = __builtin_amdgcn_mfma_f32_16x16x32_bf16(
                    a[1], bfr[jj][ct], acc[1][ct], 0, 0, 0);
            }
        }
        __builtin_amdgcn_sched_barrier(0);

        // [4] cvt + write slab s+1 into the other buffer (A-wait lands here)
        if (s + 1 < NSLAB) {
#pragma unroll
            for (int q = 0; q < 8; ++q) {
                u32x2 d;
                d[0] = pack2(v[q][0], v[q][1]);
                d[1] = pack2(v[q][2], v[q][3]);
                *reinterpret_cast<u32x2*>(AWADDR(buf ^ 1, q)) = d;
            }
        }
        __syncthreads();   // publish slab s+1
    }
#undef AWADDR

    // ---- cross-wave K reduction through LDS, two passes (28 KB overlay
    // fits the 32 KB staging buffer). Slot layout per pass = R13-verified.
    float* sf = reinterpret_cast<float*>(smem);
    const int rcol0 = (t >> 2) & 15;
    float* out_tf = out + (size_t)NROWS * CCLS;

#pragma unroll
    for (int rt = 0; rt < 2; ++rt) {
#pragma unroll
        for (int ct = 0; ct < NCT; ++ct)
            *reinterpret_cast<f32x4*>(
                sf + ((wave * NCT + ct) << 8) + (lane << 2)) = acc[rt][ct];
        __syncthreads();

        // reduce 4 partials + bias + store:
        // slot f32 index t: col = ct*16 + ((t>>2)&15), Mrow = ((t>>6)<<2)+(t&3)
        const long grow = rw + rt * 16 + ((t >> 6) << 2) + (t & 3);
#pragma unroll
        for (int ct = 0; ct < NCT; ++ct) {
            const int col = ct * 16 + rcol0;
            if (col >= NCOL) continue;
            const float v = sf[(0 * NCT + ct) * 256 + t] +
                            sf[(1 * NCT + ct) * 256 + t] +
                            sf[(2 * NCT + ct) * 256 + t] +
                            sf[(3 * NCT + ct) * 256 + t] +
                            ((col < CCLS) ? bcls[col] : btf[col - CCLS]);
            if (col < CCLS) out[grow * CCLS + col] = v;
            else            out_tf[grow * CTF + (col - CCLS)] = v;
        }
        __syncthreads();   // pass rt consumed before pass rt+1 overwrites
    }
}

extern "C" void kernel_launch(void* const* d_in, const int* in_sizes, int n_in,
                              void* d_out, int out_size, void* d_ws, size_t ws_size,
                              hipStream_t stream) {
    const float* F  = (const float*)d_in[0];
    const float* Wc = (const float*)d_in[1];
    const float* bc = (const float*)d_in[2];
    const float* Wt = (const float*)d_in[3];
    const float* bt = (const float*)d_in[4];
    unsigned short* Bp = (unsigned short*)d_ws;   // 229,376 B

    pack_B_kernel<<<NCT * (DK / 32), 64, 0, stream>>>(Wc, Wt, Bp);
    roi_gemm_kernel<<<NROWS / BM, 256, 0, stream>>>(F, Bp, bc, bt,
                                                    (float*)d_out);
}

// Round 18
// 145.748 us; speedup vs baseline: 1.1810x; 1.1810x over previous
//
#include <hip/hip_runtime.h>
#include <hip/hip_bf16.h>

#define NROWS 131072
#define DK    1024
#define CCLS  21
#define CTF   84
#define NCOL  105          // 21 + 84
#define NCT   7            // 112 padded cols / 16
#define BM    16           // rows per block = one MFMA row-tile
#define SLABF 256          // f32 per row per slab = 1KB contiguous per load
#define NSLAB (DK / SLABF) // 4

typedef __attribute__((ext_vector_type(4))) float f32x4;
typedef __attribute__((ext_vector_type(8))) short bf16x8;
typedef __attribute__((ext_vector_type(2))) unsigned int u32x2;

__device__ __forceinline__ unsigned short f2bf_rne(float x) {
    union { float f; unsigned u; } v; v.f = x;
    unsigned r = v.u + 0x7fffu + ((v.u >> 16) & 1u);
    return (unsigned short)(r >> 16);
}

__device__ __forceinline__ unsigned pack2(float lo, float hi) {
    union { float f; unsigned u; } a, b; a.f = lo; b.f = hi;
    return ((a.u + 0x8000u) >> 16) | ((b.u + 0x8000u) & 0xffff0000u);
}

// Pack [W_cls | W_tf | zero-pad] into bf16 MFMA B-fragment order (verified):
// element ((kt*NCT+ct)*64+lane)*8 + j = B[k][col],
// col = ct*16 + (lane&15), k = kt*32 + (lane>>4)*8 + j
__global__ void pack_B_kernel(const float* __restrict__ Wc,
                              const float* __restrict__ Wt,
                              unsigned short* __restrict__ Bp) {
    const int frag = blockIdx.x;           // 224 total
    const int kt = frag / NCT, ct = frag % NCT;
    const int lane = threadIdx.x;          // 64
    const int col = ct * 16 + (lane & 15);
    const int k0  = kt * 32 + ((lane >> 4) << 3);
    bf16x8 o;
#pragma unroll
    for (int j = 0; j < 8; ++j) {
        const int k = k0 + j;
        float v = 0.0f;
        if (col < CCLS)      v = Wc[k * CCLS + col];
        else if (col < NCOL) v = Wt[k * CTF + (col - CCLS)];
        o[j] = (short)f2bf_rne(v);
    }
    *reinterpret_cast<bf16x8*>(Bp + ((size_t)frag * 64 + lane) * 8) = o;
}

// R13 (measured best, 145.1 us, reproduced x2): reg-staged GEMM with
// FIFO-correct prefetch. Per slab, issue order is [B x14][A(s+1) x4] so
// compute's B-waits retire ONLY B (vmcnt FIFO) and the A prefetch stays in
// flight through compute + write. VGPR loads (probe-proven 6.3 TB/s path),
// 1KB contiguous per instruction. XOR-swizzled LDS on both sides.
// 16 waves/CU (launch_bounds 256,4) — TLP is the binding latency-hider.
__global__ __launch_bounds__(256, 4)
void roi_gemm_kernel(const float* __restrict__ F,
                     const unsigned short* __restrict__ Bp,
                     const float* __restrict__ bcls,
                     const float* __restrict__ btf,
                     float* __restrict__ out) {
    // staging: 2 bufs x 16 rows x 512B bf16 = 16 KB; reduce overlay = 28 KB
    __shared__ __align__(16) unsigned char smem[28672];

    const int t    = threadIdx.x;
    const int wave = t >> 6;
    const int lane = t & 63;
    const int fr   = lane & 15;      // A row-in-tile / B col
    const int fq   = lane >> 4;      // 0..3
    const long rw  = (long)blockIdx.x * BM;

    const unsigned short* bb = Bp + (size_t)lane * 8;
    // wave stages rows wave*4..wave*4+3; lane covers 16B at col lane*4
    const float* abase = F + (size_t)(rw + wave * 4) * DK + lane * 4;

    f32x4 acc[NCT];
#pragma unroll
    for (int ct = 0; ct < NCT; ++ct) acc[ct] = (f32x4){0.f, 0.f, 0.f, 0.f};

    // LDS addresses (bf16 tile, 512B/row, 16B-chunk XOR swizzle by row&7):
    //  write row R=wave*4+q: byte = buf*8192 + R*512
    //        + (((lane>>1) ^ (R&7))<<4) + ((lane&1)<<3)
    //  read  k-tile lt:      byte = buf*8192 + fr*512
    //        + ((((lt<<2)|fq) ^ (fr&7))<<4)
#define AWADDR(BUF, Q) (smem + (BUF) * 8192 + (wave * 4 + (Q)) * 512 +        \
    (((lane >> 1) ^ ((wave * 4 + (Q)) & 7)) << 4) + ((lane & 1) << 3))

    // ---- prologue: load + write slab 0
    {
        f32x4 v0[4];
#pragma unroll
        for (int q = 0; q < 4; ++q)
            v0[q] = *reinterpret_cast<const f32x4*>(abase + (size_t)q * DK);
#pragma unroll
        for (int q = 0; q < 4; ++q) {
            u32x2 d;
            d[0] = pack2(v0[q][0], v0[q][1]);
            d[1] = pack2(v0[q][2], v0[q][3]);
            *reinterpret_cast<u32x2*>(AWADDR(0, q)) = d;
        }
    }
    __syncthreads();

#pragma unroll
    for (int s = 0; s < NSLAB; ++s) {
        const int buf = s & 1;

        // [1] ALL B-fragment loads for slab s — FIRST in the VMEM FIFO
        bf16x8 bfr[2][NCT];
#pragma unroll
        for (int jj = 0; jj < 2; ++jj) {
            const int ktg = s * 8 + wave * 2 + jj;
#pragma unroll
            for (int ct = 0; ct < NCT; ++ct)
                bfr[jj][ct] = *reinterpret_cast<const bf16x8*>(
                    bb + ((size_t)(ktg * NCT + ct) * 512));
        }
        __builtin_amdgcn_sched_barrier(0);

        // [2] A prefetch for slab s+1 — AFTER B, so B-waits keep it in flight
        f32x4 v[4];
        if (s + 1 < NSLAB) {
#pragma unroll
            for (int q = 0; q < 4; ++q)
                v[q] = *reinterpret_cast<const f32x4*>(
                    abase + (size_t)q * DK + (s + 1) * SLABF);
        }
        __builtin_amdgcn_sched_barrier(0);

        // [3] compute slab s (B-waits are counted: vmcnt retires only B)
#pragma unroll
        for (int jj = 0; jj < 2; ++jj) {
            const int lt = wave * 2 + jj;
            const bf16x8 a = *reinterpret_cast<const bf16x8*>(
                smem + buf * 8192 + fr * 512 +
                ((((lt << 2) | fq) ^ (fr & 7)) << 4));
#pragma unroll
            for (int ct = 0; ct < NCT; ++ct)
                acc[ct] = __builtin_amdgcn_mfma_f32_16x16x32_bf16(
                    a, bfr[jj][ct], acc[ct], 0, 0, 0);
        }
        __builtin_amdgcn_sched_barrier(0);

        // [4] cvt + write slab s+1 into the other buffer (A-wait lands here)
        if (s + 1 < NSLAB) {
#pragma unroll
            for (int q = 0; q < 4; ++q) {
                u32x2 d;
                d[0] = pack2(v[q][0], v[q][1]);
                d[1] = pack2(v[q][2], v[q][3]);
                *reinterpret_cast<u32x2*>(AWADDR(buf ^ 1, q)) = d;
            }
        }
        __syncthreads();   // publish slab s+1 (outstanding VMEM is 0 here)
    }
#undef AWADDR

    // ---- cross-wave K reduction through LDS (overlay; verified in R12)
    float* sf = reinterpret_cast<float*>(smem);
#pragma unroll
    for (int ct = 0; ct < NCT; ++ct)
        *reinterpret_cast<f32x4*>(sf + ((wave * NCT + ct) << 8) + (lane << 2)) =
            acc[ct];
    __syncthreads();

    // reduce 4 partials + bias + store (verified in R12):
    // slot f32 index t: col = ct*16 + ((t>>2)&15), Mrow = ((t>>6)<<2)+(t&3)
    const int rcol0 = (t >> 2) & 15;
    float* out_tf = out + (size_t)NROWS * CCLS;
    const long grow = rw + ((t >> 6) << 2) + (t & 3);
#pragma unroll
    for (int ct = 0; ct < NCT; ++ct) {
        const int col = ct * 16 + rcol0;
        if (col >= NCOL) continue;
        const float v = sf[(0 * NCT + ct) * 256 + t] +
                        sf[(1 * NCT + ct) * 256 + t] +
                        sf[(2 * NCT + ct) * 256 + t] +
                        sf[(3 * NCT + ct) * 256 + t] +
                        ((col < CCLS) ? bcls[col] : btf[col - CCLS]);
        if (col < CCLS) out[grow * CCLS + col] = v;
        else            out_tf[grow * CTF + (col - CCLS)] = v;
    }
}

extern "C" void kernel_launch(void* const* d_in, const int* in_sizes, int n_in,
                              void* d_out, int out_size, void* d_ws, size_t ws_size,
                              hipStream_t stream) {
    const float* F  = (const float*)d_in[0];
    const float* Wc = (const float*)d_in[1];
    const float* bc = (const float*)d_in[2];
    const float* Wt = (const float*)d_in[3];
    const float* bt = (const float*)d_in[4];
    unsigned short* Bp = (unsigned short*)d_ws;   // 229,376 B

    pack_B_kernel<<<NCT * (DK / 32), 64, 0, stream>>>(Wc, Wt, Bp);
    roi_gemm_kernel<<<NROWS / BM, 256, 0, stream>>>(F, Bp, bc, bt,
                                                    (float*)d_out);
}